// Round 3
// baseline (160.364 us; speedup 1.0000x reference)
//
#include <hip/hip_runtime.h>
#include <math.h>

// Problem constants
#define BB 32
#define TT 1024
#define DD 256
#define NBLK1 1024          // partial blocks; 32 rows each (never straddles b)
#define CHUNKS_PER_B 32     // 1024 / 32

// Ready-flag magic: bytes all distinct, cannot collide with repeated-byte or
// NaN poison patterns. k_apply resets flags to 0 for replay robustness.
#define FLAG_MAGIC 0xA5B4C3D21F2E3D4CULL

// Analytic collapse (verified in prior session):
//   out[b,t,d] = (t < len[b]) ? (1+W[b,d])*x[b,t,d] + (t==0 ? Bf[b,d] : 0) : 0
// where c = (sum_t x)/len, W = MLP_W(c), Bf = MLP_B(c), exact GELU.
//
// R1 post-mortem: acquire/threadfence at agent scope lower to buffer_inv /
// buffer_wbl2 — L2-maintenance storm in the spin (125us, 2% HBM).
// R2 post-mortem: relaxed agent-scope STORES do not reliably write through
// the producer XCD's L2; flags/partials became visible only on natural L2
// writeback (~55us idle spin; VALUBusy 0.8%, HBM 4%).
// R3: ALL cross-block traffic uses atomic RMWs, which execute at the
// coherence point (memory-side) on CDNA — the same mechanism that makes
// device-scope atomicAdd work across XCDs. No fences, no buffer_inv, and
// visibility is immediate once vmcnt drains (at __syncthreads).

// ---------------------------------------------------------------------------
// K1 (fused): partial[g][d] = sum of 32 consecutive rows of x; publish via
// u64 atomicExch + MAGIC flag (atomicExch). Chunks 30/31 of each b poll the
// b's 32 flags with RMW reads (atomicAdd+0), reduce c[b] from partials (RMW
// reads), and run one 2-layer exact-GELU MLP each (30 -> Wout, 31 -> Bout).
// Deadlock-free: 1024 blocks, 4 waves, low VGPR, 8KB LDS -> all co-resident;
// and producers never wait, so forward progress is unconditional anyway.
// ---------------------------------------------------------------------------
__global__ __launch_bounds__(256)
void k_fused(const float* __restrict__ x, const int* __restrict__ len,
             const float* __restrict__ Ww1_w, const float* __restrict__ Ww1_b,
             const float* __restrict__ Ww2_w, const float* __restrict__ Ww2_b,
             const float* __restrict__ Wb1_w, const float* __restrict__ Wb1_b,
             const float* __restrict__ Wb2_w, const float* __restrict__ Wb2_b,
             unsigned long long* __restrict__ partial,   // [1024][128] u64 (=2 floats)
             unsigned long long* __restrict__ flags,     // [1024]
             float* __restrict__ Wout, float* __restrict__ Bout) {
    __shared__ float4 red[4][64];
    __shared__ float  cred[2][DD];
    __shared__ float  csh[DD];
    __shared__ float  hsh[DD];
    const int g    = blockIdx.x;
    const int tid  = threadIdx.x;
    const int wave = tid >> 6;
    const int lane = tid & 63;
    const int row0 = g * 32;
    const int b    = g >> 5;    // batch this chunk belongs to
    const int j    = g & 31;    // chunk index within b

    // --- partial sum of 32 rows ---
    const float4* xr = (const float4*)(x + (size_t)(row0 + wave * 8) * DD);
    float4 s; s.x = 0.f; s.y = 0.f; s.z = 0.f; s.w = 0.f;
#pragma unroll
    for (int r = 0; r < 8; ++r) {
        float4 v = xr[(size_t)r * 64 + lane];
        s.x += v.x; s.y += v.y; s.z += v.z; s.w += v.w;
    }
    red[wave][lane] = s;
    __syncthreads();
    if (tid < 64) {
        float4 a = red[0][tid], b4 = red[1][tid], c4 = red[2][tid], d4 = red[3][tid];
        float4 o;
        o.x = (a.x + b4.x) + (c4.x + d4.x);
        o.y = (a.y + b4.y) + (c4.y + d4.y);
        o.z = (a.z + b4.z) + (c4.z + d4.z);
        o.w = (a.w + b4.w) + (c4.w + d4.w);
        // Memory-side publication: atomic RMW executes at the coherence point.
        unsigned long long* pg = partial + (size_t)g * (DD / 2);
        unsigned long long p0 = (((unsigned long long)__float_as_uint(o.y)) << 32) | __float_as_uint(o.x);
        unsigned long long p1 = (((unsigned long long)__float_as_uint(o.w)) << 32) | __float_as_uint(o.z);
        atomicExch(&pg[tid * 2 + 0], p0);
        atomicExch(&pg[tid * 2 + 1], p1);
    }
    __syncthreads();              // s_waitcnt vmcnt(0): partial RMWs committed memory-side

    // --- publish flag (RMW, memory-side, ordered after partials by the drain above) ---
    if (tid == 0) {
        atomicExch(&flags[g], (unsigned long long)FLAG_MAGIC);
    }

    if (j < 30) return;           // only chunks 30/31 of each b do the fixup

    // --- poll all 32 chunk flags of this b (RMW reads at coherence point) ---
    if (tid < 32) {
        unsigned long long* fb = flags + b * CHUNKS_PER_B;
        while (atomicAdd(&fb[tid], 0ULL) != (unsigned long long)FLAG_MAGIC) {
            __builtin_amdgcn_s_sleep(1);   // ~64cy backoff
        }
    }
    __syncthreads();

    // --- c[b][d] = (sum over 32 chunks of partial)/len, via RMW reads ---
    {
        const int k    = tid & 127;   // u64 index within a chunk (covers d=2k, 2k+1)
        const int half = tid >> 7;    // 0: chunks 0..15, 1: chunks 16..31
        unsigned long long* pb = partial + (size_t)b * CHUNKS_PER_B * (DD / 2);
        float slo = 0.f, shi = 0.f;
#pragma unroll
        for (int ch = 0; ch < 16; ++ch) {
            unsigned long long v =
                atomicAdd(&pb[(size_t)(half * 16 + ch) * (DD / 2) + k], 0ULL);
            slo += __uint_as_float((unsigned)(v & 0xffffffffULL));
            shi += __uint_as_float((unsigned)(v >> 32));
        }
        cred[half][2 * k]     = slo;
        cred[half][2 * k + 1] = shi;
    }
    __syncthreads();
    csh[tid] = (cred[0][tid] + cred[1][tid]) / (float)len[b];
    __syncthreads();

    const int mlp   = j & 1;      // j==30 -> W-MLP, j==31 -> B-MLP
    const float* w1 = mlp ? Wb1_w : Ww1_w;
    const float* b1 = mlp ? Wb1_b : Ww1_b;
    const float* w2 = mlp ? Wb2_w : Ww2_w;
    const float* b2 = mlp ? Wb2_b : Ww2_b;
    float* op       = mlp ? Bout  : Wout;
    {   // layer 1: h[j] = gelu_exact(c . w1[j] + b1[j])
        const float4* wr = (const float4*)(w1 + (size_t)tid * DD);
        const float4* cc = (const float4*)csh;
        float sum = 0.f;
#pragma unroll 8
        for (int k = 0; k < 64; ++k) {
            float4 w = wr[k];
            float4 c4 = cc[k];
            sum += w.x * c4.x + w.y * c4.y + w.z * c4.z + w.w * c4.w;
        }
        float v = sum + b1[tid];
        hsh[tid] = 0.5f * v * (1.0f + erff(v * 0.70710678118654752440f));
    }
    __syncthreads();
    {   // layer 2: op[b][d] = h . w2[d] + b2[d]
        const float4* wr = (const float4*)(w2 + (size_t)tid * DD);
        const float4* hh = (const float4*)hsh;
        float sum = 0.f;
#pragma unroll 8
        for (int k = 0; k < 64; ++k) {
            float4 w = wr[k];
            float4 h4 = hh[k];
            sum += w.x * h4.x + w.y * h4.y + w.z * h4.z + w.w * h4.w;
        }
        op[b * DD + tid] = sum + b2[tid];
    }
}

// ---------------------------------------------------------------------------
// K2: out[b,t,d] = (t<L) ? (1+W[b,d])*x + (t==0 ? B[b,d] : 0) : 0
// 8192 blocks x 256 threads; one wave per row, float4 per lane.
// Also resets the 1024 ready flags (belt+braces; ws re-poison normally
// guarantees non-MAGIC anyway). End-of-dispatch flush publishes the reset.
// ---------------------------------------------------------------------------
__global__ __launch_bounds__(256)
void k_apply(const float* __restrict__ x, const int* __restrict__ len,
             const float* __restrict__ Wf, const float* __restrict__ Bf,
             unsigned long long* __restrict__ flags,
             float* __restrict__ out) {
    if (threadIdx.x == 0 && blockIdx.x < NBLK1) flags[blockIdx.x] = 0ULL;
    const int row  = blockIdx.x * 4 + (threadIdx.x >> 6);
    const int lane = threadIdx.x & 63;
    const int b = row >> 10;
    const int t = row & (TT - 1);
    const int L = len[b];
    const size_t base = (size_t)row * DD;
    float4* o4 = (float4*)(out + base);
    if (t >= L) {
        float4 z; z.x = 0.f; z.y = 0.f; z.z = 0.f; z.w = 0.f;
        o4[lane] = z;
        return;
    }
    float4 x4 = ((const float4*)(x + base))[lane];
    float4 w4 = ((const float4*)(Wf + b * DD))[lane];
    float4 r;
    r.x = x4.x + w4.x * x4.x;
    r.y = x4.y + w4.y * x4.y;
    r.z = x4.z + w4.z * x4.z;
    r.w = x4.w + w4.w * x4.w;
    if (t == 0) {
        float4 b4 = ((const float4*)(Bf + b * DD))[lane];
        r.x += b4.x; r.y += b4.y; r.z += b4.z; r.w += b4.w;
    }
    o4[lane] = r;
}

// Workspace (floats): partial [1024][256] = 262144 @0,
// flags 1024 x u64 = 2048 floats @262144 (8B-aligned: 1 MiB offset),
// Wout @264192 (8192), Bout @272384 (8192).
extern "C" void kernel_launch(void* const* d_in, const int* in_sizes, int n_in,
                              void* d_out, int out_size, void* d_ws, size_t ws_size,
                              hipStream_t stream) {
    const float* x     = (const float*)d_in[0];
    const int*   len   = (const int*)d_in[1];
    const float* Ww1_w = (const float*)d_in[2];
    const float* Ww1_b = (const float*)d_in[3];
    const float* Ww2_w = (const float*)d_in[4];
    const float* Ww2_b = (const float*)d_in[5];
    const float* Wb1_w = (const float*)d_in[6];
    const float* Wb1_b = (const float*)d_in[7];
    const float* Wb2_w = (const float*)d_in[8];
    const float* Wb2_b = (const float*)d_in[9];
    float* out = (float*)d_out;

    float* ws = (float*)d_ws;
    unsigned long long* partial = (unsigned long long*)ws;            // 1 MiB
    unsigned long long* flags   = (unsigned long long*)(ws + 262144); // 8 KiB
    float* Wout = ws + 262144 + 2048;
    float* Bout = Wout + 8192;

    k_fused<<<NBLK1, 256, 0, stream>>>(x, len,
                                       Ww1_w, Ww1_b, Ww2_w, Ww2_b,
                                       Wb1_w, Wb1_b, Wb2_w, Wb2_b,
                                       partial, flags, Wout, Bout);
    k_apply<<<BB * TT / 4, 256, 0, stream>>>(x, len, Wout, Bout, flags, out);
}

// Round 4
// 118.024 us; speedup vs baseline: 1.3587x; 1.3587x over previous
//
#include <hip/hip_runtime.h>
#include <math.h>

// Problem constants
#define BB 32
#define TT 1024
#define DD 256
#define NBLK1 1024          // k_partial blocks; 32 rows each (never straddles b)
#define CHUNKS_PER_B 32     // 1024 / 32

// Analytic collapse (verified round 1 of prior session):
//   out[b,t,d] = (t < len[b]) ? (1+W[b,d])*x[b,t,d] + (t==0 ? Bf[b,d] : 0) : 0
// where c = (sum_t x)/len, W = MLP_W(c), Bf = MLP_B(c), exact GELU.
//
// Structure: 3 stream-ordered dispatches. Fusion attempts are all measured
// dead ends on this part:
//  - cooperative grid.sync(): ~100us/barrier (prior session)
//  - spin-on-flag fusion, acquire/threadfence: 125us (buffer_inv storm, R1)
//  - spin-on-flag, relaxed sc1 stores: 66us (R2)
//  - spin-on-flag, memory-side atomic RMW: 66us (R3)
// R2==R3 profile => the ~55us spinner tail is invariant to the coherence
// mechanism; inter-block sync costs O(50-100us) here regardless of spelling.
// The 3-dispatch pipeline's controllable cost is ~20-25us; the rest of the
// timed window is harness re-poison fills running at the achievable HBM
// ceiling (6.2-6.3 TB/s). This is the floor.

// ---------------------------------------------------------------------------
// K1: partial[g][d] = sum of 32 consecutive rows of x. 1024 blocks x 256 thr.
// Each wave sums 8 rows as float4; LDS combine across the 4 waves.
// ---------------------------------------------------------------------------
__global__ __launch_bounds__(256)
void k_partial(const float* __restrict__ x, float* __restrict__ partial) {
    __shared__ float4 red[4][64];
    const int g    = blockIdx.x;
    const int tid  = threadIdx.x;
    const int wave = tid >> 6;
    const int lane = tid & 63;
    const int row0 = g * 32;

    const float4* xr = (const float4*)(x + (size_t)(row0 + wave * 8) * DD);
    float4 s; s.x = 0.f; s.y = 0.f; s.z = 0.f; s.w = 0.f;
#pragma unroll
    for (int r = 0; r < 8; ++r) {
        float4 v = xr[(size_t)r * 64 + lane];
        s.x += v.x; s.y += v.y; s.z += v.z; s.w += v.w;
    }
    red[wave][lane] = s;
    __syncthreads();
    if (tid < 64) {
        float4 a = red[0][tid], b = red[1][tid], c = red[2][tid], d = red[3][tid];
        float4 o;
        o.x = (a.x + b.x) + (c.x + d.x);
        o.y = (a.y + b.y) + (c.y + d.y);
        o.z = (a.z + b.z) + (c.z + d.z);
        o.w = (a.w + b.w) + (c.w + d.w);
        ((float4*)(partial + (size_t)g * DD))[tid] = o;
    }
}

// ---------------------------------------------------------------------------
// K2: 64 blocks -> block (b, mlp): c[b] = sum(partial)/len, then 2-layer MLP
// with exact GELU, all in LDS. mlp0 -> Wout, mlp1 -> Bout.
// ---------------------------------------------------------------------------
__global__ __launch_bounds__(256)
void k_mlp(const float* __restrict__ partial, const int* __restrict__ len,
           const float* __restrict__ Ww1_w, const float* __restrict__ Ww1_b,
           const float* __restrict__ Ww2_w, const float* __restrict__ Ww2_b,
           const float* __restrict__ Wb1_w, const float* __restrict__ Wb1_b,
           const float* __restrict__ Wb2_w, const float* __restrict__ Wb2_b,
           float* __restrict__ Wout, float* __restrict__ Bout) {
    __shared__ float csh[DD];
    __shared__ float hsh[DD];
    const int tid = threadIdx.x;
    const int b   = blockIdx.x >> 1;
    const int mlp = blockIdx.x & 1;

    {   // c[b][tid]
        float s = 0.f;
        const float* pp = partial + (size_t)(b * CHUNKS_PER_B) * DD + tid;
#pragma unroll
        for (int ch = 0; ch < CHUNKS_PER_B; ++ch) s += pp[(size_t)ch * DD];
        csh[tid] = s / (float)len[b];
    }
    __syncthreads();
    const float* w1 = mlp ? Wb1_w : Ww1_w;
    const float* b1 = mlp ? Wb1_b : Ww1_b;
    const float* w2 = mlp ? Wb2_w : Ww2_w;
    const float* b2 = mlp ? Wb2_b : Ww2_b;
    float* op       = mlp ? Bout  : Wout;
    {   // layer 1: h[j] = gelu_exact(c . w1[j] + b1[j])
        const float4* wr = (const float4*)(w1 + (size_t)tid * DD);
        const float4* cc = (const float4*)csh;
        float s = 0.f;
#pragma unroll 8
        for (int k = 0; k < 64; ++k) {
            float4 w = wr[k];
            float4 c4 = cc[k];
            s += w.x * c4.x + w.y * c4.y + w.z * c4.z + w.w * c4.w;
        }
        float v = s + b1[tid];
        hsh[tid] = 0.5f * v * (1.0f + erff(v * 0.70710678118654752440f));
    }
    __syncthreads();
    {   // layer 2: op[b][d] = h . w2[d] + b2[d]
        const float4* wr = (const float4*)(w2 + (size_t)tid * DD);
        const float4* hh = (const float4*)hsh;
        float s = 0.f;
#pragma unroll 8
        for (int k = 0; k < 64; ++k) {
            float4 w = wr[k];
            float4 h4 = hh[k];
            s += w.x * h4.x + w.y * h4.y + w.z * h4.z + w.w * h4.w;
        }
        op[b * DD + tid] = s + b2[tid];
    }
}

// ---------------------------------------------------------------------------
// K3: out[b,t,d] = (t<L) ? (1+W[b,d])*x + (t==0 ? B[b,d] : 0) : 0
// 8192 blocks x 256 threads; one wave per row, float4 per lane.
// ---------------------------------------------------------------------------
__global__ __launch_bounds__(256)
void k_apply(const float* __restrict__ x, const int* __restrict__ len,
             const float* __restrict__ Wf, const float* __restrict__ Bf,
             float* __restrict__ out) {
    const int row  = blockIdx.x * 4 + (threadIdx.x >> 6);
    const int lane = threadIdx.x & 63;
    const int b = row >> 10;
    const int t = row & (TT - 1);
    const int L = len[b];
    const size_t base = (size_t)row * DD;
    float4* o4 = (float4*)(out + base);
    if (t >= L) {
        float4 z; z.x = 0.f; z.y = 0.f; z.z = 0.f; z.w = 0.f;
        o4[lane] = z;
        return;
    }
    float4 x4 = ((const float4*)(x + base))[lane];
    float4 w4 = ((const float4*)(Wf + b * DD))[lane];
    float4 r;
    r.x = x4.x + w4.x * x4.x;
    r.y = x4.y + w4.y * x4.y;
    r.z = x4.z + w4.z * x4.z;
    r.w = x4.w + w4.w * x4.w;
    if (t == 0) {
        float4 b4 = ((const float4*)(Bf + b * DD))[lane];
        r.x += b4.x; r.y += b4.y; r.z += b4.z; r.w += b4.w;
    }
    o4[lane] = r;
}

// Workspace (floats): partial [1024][256] = 262144, Wout @262144 (8192),
// Bout @270336 (8192).
extern "C" void kernel_launch(void* const* d_in, const int* in_sizes, int n_in,
                              void* d_out, int out_size, void* d_ws, size_t ws_size,
                              hipStream_t stream) {
    const float* x     = (const float*)d_in[0];
    const int*   len   = (const int*)d_in[1];
    const float* Ww1_w = (const float*)d_in[2];
    const float* Ww1_b = (const float*)d_in[3];
    const float* Ww2_w = (const float*)d_in[4];
    const float* Ww2_b = (const float*)d_in[5];
    const float* Wb1_w = (const float*)d_in[6];
    const float* Wb1_b = (const float*)d_in[7];
    const float* Wb2_w = (const float*)d_in[8];
    const float* Wb2_b = (const float*)d_in[9];
    float* out = (float*)d_out;

    float* ws      = (float*)d_ws;
    float* partial = ws;
    float* Wout    = ws + 262144;
    float* Bout    = ws + 270336;

    k_partial<<<NBLK1, 256, 0, stream>>>(x, partial);
    k_mlp<<<2 * BB, 256, 0, stream>>>(partial, len,
                                      Ww1_w, Ww1_b, Ww2_w, Ww2_b,
                                      Wb1_w, Wb1_b, Wb2_w, Wb2_b,
                                      Wout, Bout);
    k_apply<<<BB * TT / 4, 256, 0, stream>>>(x, len, Wout, Bout, out);
}